// Round 1
// 656.004 us; speedup vs baseline: 1.3297x; 1.3297x over previous
//
#include <hip/hip_runtime.h>

// Sinkhorn divergence, 512 independent 256-point problems, 24 annealing steps.
// Round 3: single-pass online logsumexp. Args for a chunk of 8 columns are
// held in registers; the running row max is quantized to an integer-valued
// float (ceilf) so the cross-chunk rescale of the partial sum is a single
// v_ldexp_f32 (VALU) instead of an exp2 (trans). This removes the arg
// recompute + second LDS sweep of the old two-pass scheme (4 -> 2
// ds_read_b128/col, 29 -> ~24 VALU/col) and merges the max/sum barriers
// (3 -> 2 barriers per step). exp2 count per element is unchanged (1.0).
//
// Math (log2 domain, per softmin with rows P / cols Q, col-potential h):
//   softmin_i = 0.5||P_i||^2 - eps*ln2*( M_i + log2 sum_j 2^{arg_ij - M_i} )
//   arg_ij    = H2[j] + t_i*t_j*inv + p_i*q_j*inv ,  inv = log2e/eps
//   H2[j]     = -8 + (h[j] - 0.5||Q_j||^2)*inv        (la*log2e = -log2 256)
// M_i is any integer-valued float >= max_j arg_ij (exact identity, no
// overflow: shifted args <= 0, dominant term >= 2^-1).

constexpr int   N       = 256;   // points per cloud
constexpr int   NPROB   = 512;   // B*S*NR
constexpr int   NRDIM   = 64;
constexpr float DT_F    = 0.001f;
constexpr float EPS_MIN = 1e-4f; // BLUR^P
constexpr int   NSTEPS  = 24;
constexpr float LOG2E   = 1.4426950408889634f;
constexpr float LN2     = 0.6931471805599453f;
constexpr int   NT      = 1024;  // threads per block
constexpr int   CPQ     = 64;    // columns per quarter

extern "C" __global__ void __launch_bounds__(NT, 8)
sinkhorn_div_kernel(const float* __restrict__ syn,
                    const float* __restrict__ obs,
                    float* __restrict__ divs)
{
    const int p   = blockIdx.x;          // ((b*S + s)*NR + r)
    const int r   = p & (NRDIM - 1);
    const int bs  = p >> 6;
    const int tid = threadIdx.x;
    const int row = tid & (N - 1);       // row index i (duplicated x4)
    const int q   = tid >> 8;            // column quarter 0..3

    __shared__ float4 ya[N];             // (Hxy, Hyy, y_j*inv, 0)
    __shared__ float4 xa[N];             // (Hyx, Hxx, x_j*inv, 0)
    __shared__ float4 msh[NT];           // per-thread (m_xy, m_yy, s_xy, s_yy)
    __shared__ float4 ssh[NT];           // per-thread (m_yx, m_xx, s_yx, s_xx)
    __shared__ float  redA[64];

    const size_t base = (size_t)bs * N * NRDIM + r;
    const float xi = obs[base + (size_t)row * NRDIM];   // x cloud = obs
    const float yi = syn[base + (size_t)row * NRDIM];   // y cloud = syn

    // ---- block reductions: diameter (max/min) + all-zero mask sums ----
    float hi = fmaxf(xi, yi), lo = fminf(xi, yi);
    float ax = fabsf(xi),     ay = fabsf(yi);
    #pragma unroll
    for (int off = 32; off > 0; off >>= 1) {
        hi  = fmaxf(hi, __shfl_down(hi, off, 64));
        lo  = fminf(lo, __shfl_down(lo, off, 64));
        ax += __shfl_down(ax, off, 64);
        ay += __shfl_down(ay, off, 64);
    }
    const int wave = tid >> 6;           // 0..15
    if ((tid & 63) == 0) {
        redA[wave * 4 + 0] = hi;  redA[wave * 4 + 1] = lo;
        redA[wave * 4 + 2] = ax;  redA[wave * 4 + 3] = ay;
    }
    __syncthreads();
    float vmax = -3.4e38f, vmin = 3.4e38f, sax = 0.0f, say = 0.0f;
    #pragma unroll
    for (int w = 0; w < 16; ++w) {
        vmax = fmaxf(vmax, redA[w * 4 + 0]);
        vmin = fminf(vmin, redA[w * 4 + 1]);
        sax += redA[w * 4 + 2];
        say += redA[w * 4 + 3];
    }

    const float tspread  = 255.0f * DT_F;
    const float diameter = fmaxf(tspread, vmax - vmin);
    float eps_raw = diameter * diameter;              // eps0 = diameter^2

    const float ti    = (float)row * DT_F;
    const float selfx = 0.5f * (ti * ti + xi * xi);
    const float selfy = 0.5f * (ti * ti + yi * yi);

    float f = 0.0f, g = 0.0f, px = 0.0f, py = 0.0f;

    const int j0 = q * CPQ;

    for (int step = 0; step < NSTEPS; ++step) {
        const float eps = fmaxf(eps_raw, EPS_MIN);
        const float inv = LOG2E / eps;

        // ---- prologue: quarter 0 provides column j = row of all arrays ----
        if (q == 0) {
            const float la2 = -8.0f;   // log2(1/256)
            const float Hxy = fmaf(g  - selfy, inv, la2);
            const float Hyy = fmaf(py - selfy, inv, la2);
            const float Hyx = fmaf(f  - selfx, inv, la2);
            const float Hxx = fmaf(px - selfx, inv, la2);
            ya[row] = make_float4(Hxy, Hyy, yi * inv, 0.0f);
            xa[row] = make_float4(Hyx, Hxx, xi * inv, 0.0f);
        }
        __syncthreads();   // S1

        const float a = ti * DT_F * inv;      // t-term increment per j

        // ================= pass A: mats xy (xi) and yy (yi) over ya =======
        {
            float m0 = -1e9f, m1 = -1e9f, s0 = 0.0f, s1 = 0.0f;
            float rr = a * (float)j0;
            for (int cc = 0; cc < CPQ; cc += 8) {
                float b[8], c[8];
                #pragma unroll
                for (int k = 0; k < 8; ++k) {
                    const float4 yA = ya[j0 + cc + k];
                    b[k] = fmaf(xi, yA.z, yA.x + rr);   // xy
                    c[k] = fmaf(yi, yA.z, yA.y + rr);   // yy
                    rr += a;
                }
                const float mc0 = fmaxf(fmaxf(fmaxf(b[0], b[1]), fmaxf(b[2], b[3])),
                                        fmaxf(fmaxf(b[4], b[5]), fmaxf(b[6], b[7])));
                const float mc1 = fmaxf(fmaxf(fmaxf(c[0], c[1]), fmaxf(c[2], c[3])),
                                        fmaxf(fmaxf(c[4], c[5]), fmaxf(c[6], c[7])));
                const float M0 = fmaxf(m0, ceilf(mc0));   // integer-valued shift
                const float M1 = fmaxf(m1, ceilf(mc1));
                const float t0 =
                    (__builtin_amdgcn_exp2f(b[0] - M0) + __builtin_amdgcn_exp2f(b[1] - M0)) +
                    (__builtin_amdgcn_exp2f(b[2] - M0) + __builtin_amdgcn_exp2f(b[3] - M0)) +
                   ((__builtin_amdgcn_exp2f(b[4] - M0) + __builtin_amdgcn_exp2f(b[5] - M0)) +
                    (__builtin_amdgcn_exp2f(b[6] - M0) + __builtin_amdgcn_exp2f(b[7] - M0)));
                const float t1 =
                    (__builtin_amdgcn_exp2f(c[0] - M1) + __builtin_amdgcn_exp2f(c[1] - M1)) +
                    (__builtin_amdgcn_exp2f(c[2] - M1) + __builtin_amdgcn_exp2f(c[3] - M1)) +
                   ((__builtin_amdgcn_exp2f(c[4] - M1) + __builtin_amdgcn_exp2f(c[5] - M1)) +
                    (__builtin_amdgcn_exp2f(c[6] - M1) + __builtin_amdgcn_exp2f(c[7] - M1)));
                s0 = ldexpf(s0, (int)(m0 - M0)) + t0;  m0 = M0;   // integer delta
                s1 = ldexpf(s1, (int)(m1 - M1)) + t1;  m1 = M1;
            }
            msh[tid] = make_float4(m0, m1, s0, s1);
        }

        // ================= pass B: mats yx (yi) and xx (xi) over xa =======
        {
            float m2 = -1e9f, m3 = -1e9f, s2 = 0.0f, s3 = 0.0f;
            float rr = a * (float)j0;
            for (int cc = 0; cc < CPQ; cc += 8) {
                float b[8], c[8];
                #pragma unroll
                for (int k = 0; k < 8; ++k) {
                    const float4 xA = xa[j0 + cc + k];
                    b[k] = fmaf(yi, xA.z, xA.x + rr);   // yx
                    c[k] = fmaf(xi, xA.z, xA.y + rr);   // xx
                    rr += a;
                }
                const float mc2 = fmaxf(fmaxf(fmaxf(b[0], b[1]), fmaxf(b[2], b[3])),
                                        fmaxf(fmaxf(b[4], b[5]), fmaxf(b[6], b[7])));
                const float mc3 = fmaxf(fmaxf(fmaxf(c[0], c[1]), fmaxf(c[2], c[3])),
                                        fmaxf(fmaxf(c[4], c[5]), fmaxf(c[6], c[7])));
                const float M2 = fmaxf(m2, ceilf(mc2));
                const float M3 = fmaxf(m3, ceilf(mc3));
                const float t2 =
                    (__builtin_amdgcn_exp2f(b[0] - M2) + __builtin_amdgcn_exp2f(b[1] - M2)) +
                    (__builtin_amdgcn_exp2f(b[2] - M2) + __builtin_amdgcn_exp2f(b[3] - M2)) +
                   ((__builtin_amdgcn_exp2f(b[4] - M2) + __builtin_amdgcn_exp2f(b[5] - M2)) +
                    (__builtin_amdgcn_exp2f(b[6] - M2) + __builtin_amdgcn_exp2f(b[7] - M2)));
                const float t3 =
                    (__builtin_amdgcn_exp2f(c[0] - M3) + __builtin_amdgcn_exp2f(c[1] - M3)) +
                    (__builtin_amdgcn_exp2f(c[2] - M3) + __builtin_amdgcn_exp2f(c[3] - M3)) +
                   ((__builtin_amdgcn_exp2f(c[4] - M3) + __builtin_amdgcn_exp2f(c[5] - M3)) +
                    (__builtin_amdgcn_exp2f(c[6] - M3) + __builtin_amdgcn_exp2f(c[7] - M3)));
                s2 = ldexpf(s2, (int)(m2 - M2)) + t2;  m2 = M2;
                s3 = ldexpf(s3, (int)(m3 - M3)) + t3;  m3 = M3;
            }
            ssh[tid] = make_float4(m2, m3, s2, s3);
        }
        __syncthreads();   // S2

        // ---- combine (m,s) across the 4 quarters (identical in all) ------
        const float4 A0 = msh[row];
        const float4 A1 = msh[row + 256];
        const float4 A2 = msh[row + 512];
        const float4 A3 = msh[row + 768];
        const float4 B0 = ssh[row];
        const float4 B1 = ssh[row + 256];
        const float4 B2 = ssh[row + 512];
        const float4 B3 = ssh[row + 768];

        const float Mxy = fmaxf(fmaxf(A0.x, A1.x), fmaxf(A2.x, A3.x));
        const float Myy = fmaxf(fmaxf(A0.y, A1.y), fmaxf(A2.y, A3.y));
        const float Myx = fmaxf(fmaxf(B0.x, B1.x), fmaxf(B2.x, B3.x));
        const float Mxx = fmaxf(fmaxf(B0.y, B1.y), fmaxf(B2.y, B3.y));

        const float Sxy = (ldexpf(A0.z, (int)(A0.x - Mxy)) + ldexpf(A1.z, (int)(A1.x - Mxy)))
                        + (ldexpf(A2.z, (int)(A2.x - Mxy)) + ldexpf(A3.z, (int)(A3.x - Mxy)));
        const float Syy = (ldexpf(A0.w, (int)(A0.y - Myy)) + ldexpf(A1.w, (int)(A1.y - Myy)))
                        + (ldexpf(A2.w, (int)(A2.y - Myy)) + ldexpf(A3.w, (int)(A3.y - Myy)));
        const float Syx = (ldexpf(B0.z, (int)(B0.x - Myx)) + ldexpf(B1.z, (int)(B1.x - Myx)))
                        + (ldexpf(B2.z, (int)(B2.x - Myx)) + ldexpf(B3.z, (int)(B3.x - Myx)));
        const float Sxx = (ldexpf(B0.w, (int)(B0.y - Mxx)) + ldexpf(B1.w, (int)(B1.y - Mxx)))
                        + (ldexpf(B2.w, (int)(B2.y - Mxx)) + ldexpf(B3.w, (int)(B3.y - Mxx)));

        // ---- epilogue: every quarter computes identical new potentials ----
        const float el2 = eps * LN2;
        const float fn  = selfx - el2 * (Mxy + __builtin_amdgcn_logf(Sxy));
        const float gn  = selfy - el2 * (Myx + __builtin_amdgcn_logf(Syx));
        const float pxn = 0.5f * (px + (selfx - el2 * (Mxx + __builtin_amdgcn_logf(Sxx))));
        const float pyn = 0.5f * (py + (selfy - el2 * (Myy + __builtin_amdgcn_logf(Syy))));
        f = fn; g = gn; px = pxn; py = pyn;

        eps_raw *= 0.25f;
        // no barrier here: S1 of the next step separates the prologue write
        // (after this point) from this step's pass reads (before S2).
    }

    // ---- divergence: (1/n) * sum_i [(f-px)+(g-py)], rows duplicated x4 ----
    float contrib = (f - px) + (g - py);
    #pragma unroll
    for (int off = 32; off > 0; off >>= 1)
        contrib += __shfl_down(contrib, off, 64);
    __syncthreads();                      // redA reuse
    if ((tid & 63) == 0) redA[wave] = contrib;
    __syncthreads();
    if (tid == 0) {
        float total = 0.0f;
        #pragma unroll
        for (int w = 0; w < 16; ++w) total += redA[w];
        total *= (1.0f / (float)(4 * N));             // x4 duplication
        const bool masked_out = (sax == 0.0f) && (say == 0.0f);
        divs[p] = masked_out ? 0.0f : total;
    }
}

extern "C" __global__ void __launch_bounds__(256)
reduce_out_kernel(const float* __restrict__ divs, float* __restrict__ out)
{
    const int b   = blockIdx.x;
    const int tid = threadIdx.x;
    __shared__ float red[4];
    float v = divs[b * 256 + tid];        // 256 = S*NR problems per batch
    #pragma unroll
    for (int off = 32; off > 0; off >>= 1)
        v += __shfl_down(v, off, 64);
    if ((tid & 63) == 0) red[tid >> 6] = v;
    __syncthreads();
    if (tid == 0) out[b] = red[0] + red[1] + red[2] + red[3];
}

extern "C" void kernel_launch(void* const* d_in, const int* in_sizes, int n_in,
                              void* d_out, int out_size, void* d_ws, size_t ws_size,
                              hipStream_t stream) {
    const float* syn = (const float*)d_in[0];   // syn_data
    const float* obs = (const float*)d_in[1];   // obs_data
    float* divs = (float*)d_ws;                 // 512 floats scratch

    sinkhorn_div_kernel<<<NPROB, NT, 0, stream>>>(syn, obs, divs);
    reduce_out_kernel<<<2, 256, 0, stream>>>(divs, (float*)d_out);
}